// Round 3
// baseline (300.871 us; speedup 1.0000x reference)
//
#include <hip/hip_runtime.h>
#include <hip/hip_bf16.h>

// AttnDecoder: B=2, Lq=Lkv=2048, E=1024, H=16, D=64, scale = 0.125/sqrt(2).
// Pipeline (all bf16 MFMA, fp32 accum):
//   cast3: q,k,v fp32 -> bf16 row-major           [ws +0 .. +24MB]
//   wtrans: Wq,Wk,Wv -> bf16 W^T (N x K); Wo -> permuted W^T folding head-merge [ws +24 .. +32MB]
//   gemm8<0> (z=0..2): 256x256 8-phase GEMM -> Qh,Kh [bh][l][c], VhT [bh][c][l]
//   attn: m214-style 32x32 swapped-QK^T flash attention -> Oh [bh][l][c]
//   gemm8<1>: Oh (head-merge folded into A addressing) @ WoT' -> d_out fp32
// Workspace required: 56 MB.

typedef __attribute__((ext_vector_type(8))) short short8;    // 8 x bf16 (4 VGPR)
typedef __attribute__((ext_vector_type(4))) float f32x4;     // 16x16 accumulator
typedef __attribute__((ext_vector_type(16))) float f32x16;   // 32x32 accumulator
typedef __hip_bfloat16 bf16;

#define GLD16(g, l) __builtin_amdgcn_global_load_lds( \
    (const __attribute__((address_space(1))) void*)(g), \
    (__attribute__((address_space(3))) void*)(l), 16, 0, 0)

#define VMCNT(n) do { asm volatile("s_waitcnt vmcnt(" #n ")" ::: "memory"); \
                      __builtin_amdgcn_sched_barrier(0); } while (0)
#define BAR() do { __builtin_amdgcn_sched_barrier(0); __builtin_amdgcn_s_barrier(); \
                   __builtin_amdgcn_sched_barrier(0); } while (0)

__device__ __forceinline__ f32x4 mfma16(short8 a, short8 b, f32x4 c) {
  return __builtin_amdgcn_mfma_f32_16x16x32_bf16(a, b, c, 0, 0, 0);
}
__device__ __forceinline__ f32x16 mfma32(short8 a, short8 b, f32x16 c) {
  return __builtin_amdgcn_mfma_f32_32x32x16_bf16(a, b, c, 0, 0, 0);
}

union B8 { bf16 h[8]; int4 v; };
union B4 { bf16 h[4]; int2 v; };

#define QK_SCALE_TOT 0.08838834764831845f              /* 0.125 / sqrt(2) */
#define SC2f (QK_SCALE_TOT * 1.4426950408889634f)      /* -> exp2 domain */

__device__ __forceinline__ float fexp2(float x) {
#if __has_builtin(__builtin_amdgcn_exp2f)
  return __builtin_amdgcn_exp2f(x);
#else
  return exp2f(x);
#endif
}

__device__ __forceinline__ int cvtpk(float lo, float hi_) {
  int r;
  asm("v_cvt_pk_bf16_f32 %0, %1, %2" : "=v"(r) : "v"(lo), "v"(hi_));
  return r;
}

#define ZV16 {0.f,0.f,0.f,0.f,0.f,0.f,0.f,0.f,0.f,0.f,0.f,0.f,0.f,0.f,0.f,0.f}

// ---------------- cast q,k,v -> bf16 (vectorized, G13) ----------------
__global__ __launch_bounds__(256) void cast3_kernel(
    const float* __restrict__ q, const float* __restrict__ k,
    const float* __restrict__ v, bf16* __restrict__ out)
{
  const float* src = (blockIdx.y == 0) ? q : (blockIdx.y == 1) ? k : v;
  bf16* dst = out + (size_t)blockIdx.y * (4u << 20);
  size_t i = ((size_t)blockIdx.x * 256 + threadIdx.x) * 8;
  float4 a = *(const float4*)(src + i);
  float4 b = *(const float4*)(src + i + 4);
  B8 u;
  u.h[0] = __float2bfloat16(a.x); u.h[1] = __float2bfloat16(a.y);
  u.h[2] = __float2bfloat16(a.z); u.h[3] = __float2bfloat16(a.w);
  u.h[4] = __float2bfloat16(b.x); u.h[5] = __float2bfloat16(b.y);
  u.h[6] = __float2bfloat16(b.z); u.h[7] = __float2bfloat16(b.w);
  *(int4*)(dst + i) = u.v;
}

// ---------------- weight transpose (+ Wo head-merge permutation) ----------------
__global__ __launch_bounds__(256) void wtrans_kernel(
    const float* __restrict__ Wq, const float* __restrict__ Wk,
    const float* __restrict__ Wv, const float* __restrict__ Wo,
    bf16* __restrict__ dstbase)
{
  __shared__ bf16 ld[64][68];
  const int z = blockIdx.z;
  const float* src = (z == 0) ? Wq : (z == 1) ? Wk : (z == 2) ? Wv : Wo;
  bf16* dst = dstbase + (size_t)z * (1u << 20);
  const int k0 = blockIdx.x * 64, n0 = blockIdx.y * 64;
  const int t = threadIdx.x;
  const bool perm = (z == 3);
#pragma unroll
  for (int it = 0; it < 4; ++it) {
    int kk = it * 16 + (t >> 4);
    int K = k0 + kk;
    int j = perm ? ((K & 63) * 16 + (K >> 6)) : K;
    float4 vv = *(const float4*)(src + (size_t)j * 1024 + n0 + (t & 15) * 4);
    int c = (t & 15) * 4;
    ld[c + 0][kk] = __float2bfloat16(vv.x);
    ld[c + 1][kk] = __float2bfloat16(vv.y);
    ld[c + 2][kk] = __float2bfloat16(vv.z);
    ld[c + 3][kk] = __float2bfloat16(vv.w);
  }
  __syncthreads();
#pragma unroll
  for (int it = 0; it < 2; ++it) {
    int rr = it * 32 + (t >> 3), cc = (t & 7) * 8;
    B8 u;
#pragma unroll
    for (int e = 0; e < 8; ++e) u.h[e] = ld[rr][cc + e];
    *(int4*)(dst + (size_t)(n0 + rr) * 1024 + k0 + cc) = u.v;
  }
}

// ---------------- 256x256 8-phase GEMM (T2+T3+T4+T5), BK=64, 8 waves ----------------
// Waves: 2M x 4N; per-wave output 128x64 = acc[8][4] f32x4.
// LDS: lA/lB [2 dbuf][2 half][128x64] bf16 = 128 KiB total, st_16x32 swizzled
// (byte ^= ((byte>>9)&1)<<5) via inverse-swizzled global source + swizzled reads.
// Phase schedule per iteration i (K-tiles 2i in buf0, 2i+1 in buf1), 1 half-tile
// (2 loads/thread) staged per phase:
//   P1: A(b1,h0,2i+1)  P2: A(b1,h1,2i+1)  P3: B(b0,h0,2i+2)  P4: B(b0,h1,2i+2) vmcnt(4)
//   P5: A(b0,h0,2i+2)  P6: A(b0,h1,2i+2)  P7: B(b1,h0,2i+3)  P8: B(b1,h1,2i+3) vmcnt(4)
// vmcnt(4) at P4 leaves P3/P4 in flight (needed only at next P1); at P8 leaves
// P7/P8 (needed at next P5). Last iteration: P3..P8 stages skipped -> P4
// checkpoint must be vmcnt(0) (A(b1) from P1/P2 are the only outstanding ops).
template<int FINAL>
__global__ __launch_bounds__(512, 2) void gemm8_kernel(
    const bf16* __restrict__ Abase, const bf16* __restrict__ WTbase,
    bf16* __restrict__ Qh, bf16* __restrict__ Kh, bf16* __restrict__ VhT,
    float* __restrict__ Cout)
{
  __shared__ bf16 lA[2][2][128 * 64];
  __shared__ bf16 lB[2][2][128 * 64];
  const int t = threadIdx.x, lane = t & 63, w = t >> 6;
  const int wr = w >> 2, wc = w & 3;                 // 2M x 4N waves
  const int l15 = lane & 15, l16 = lane >> 4;
  const int rswE = ((l15 >> 2) & 1) << 4;            // read-side swizzle (elems)
  const int tN = blockIdx.x * 256, tM = blockIdx.y * 256;
  const int z = FINAL ? 0 : blockIdx.z;
  const bf16* A  = Abase  + (size_t)z * (4u << 20);
  const bf16* BT = WTbase + (size_t)z * (1u << 20);

  // staging source precompute: thread covers LDS phys bytes o = (w*2+j)*1024
  // + lane*16 of each half-tile; logical byte = o ^ ((o>>9)&1)<<5.
  int oj[2], srj[2], scj[2];
#pragma unroll
  for (int j = 0; j < 2; ++j) {
    int o = (w * 2 + j) * 1024 + lane * 16;
    int lg = o ^ (((o >> 9) & 1) << 5);
    oj[j] = o >> 1;             // LDS elem offset
    srj[j] = lg >> 7;           // source row in half-tile (0..127)
    scj[j] = (lg & 127) >> 1;   // source col elem (0..63, mult of 8)
  }
  size_t aRow[2][2], bRow[2][2];  // [half][j], elem offsets sans K-tile term
#pragma unroll
  for (int h = 0; h < 2; ++h)
#pragma unroll
    for (int j = 0; j < 2; ++j) {
      int r = tM + h * 128 + srj[j];
      if (FINAL)  // Oh[bh = b*16 + head][l][c]; K-tile kt == head kt
        aRow[h][j] = ((size_t)(r >> 11) * 16 * 2048 + (r & 2047)) * 64 + scj[j];
      else
        aRow[h][j] = (size_t)r * 1024 + scj[j];
      bRow[h][j] = (size_t)(tN + h * 128 + srj[j]) * 1024 + scj[j];
    }
  const size_t aK = FINAL ? (size_t)(2048 * 64) : 64;  // A elems per K-tile

  auto stageA_ = [&](int buf, int h, int kt) {
    GLD16(A + aRow[h][0] + (size_t)kt * aK, &lA[buf][h][oj[0]]);
    GLD16(A + aRow[h][1] + (size_t)kt * aK, &lA[buf][h][oj[1]]);
  };
  auto stageB_ = [&](int buf, int h, int kt) {
    GLD16(BT + bRow[h][0] + (size_t)kt * 64, &lB[buf][h][oj[0]]);
    GLD16(BT + bRow[h][1] + (size_t)kt * 64, &lB[buf][h][oj[1]]);
  };
  auto readA = [&](int buf, int m, int kk) -> short8 {
    return *(const short8*)&lA[buf][wr]
        [(m * 16 + l15) * 64 + ((kk * 32 + l16 * 8) ^ rswE)];
  };
  auto readB = [&](int buf, int n, int kk) -> short8 {
    return *(const short8*)&lB[buf][wc >> 1]
        [((wc & 1) * 64 + n * 16 + l15) * 64 + ((kk * 32 + l16 * 8) ^ rswE)];
  };

  f32x4 acc[8][4];
#pragma unroll
  for (int m = 0; m < 8; ++m)
#pragma unroll
    for (int n = 0; n < 4; ++n) acc[m][n] = {0.f, 0.f, 0.f, 0.f};

  // prologue: B0(kt0), A0(kt0), B1(kt1); allow B1's 4 ops outstanding.
  stageB_(0, 0, 0); stageB_(0, 1, 0);
  stageA_(0, 0, 0); stageA_(0, 1, 0);
  stageB_(1, 0, 1); stageB_(1, 1, 1);
  VMCNT(4);
  BAR();

  const int NIT = 8;  // K = 1024 = NIT * 128
  for (int i = 0; i < NIT; ++i) {
    const bool more = (i + 1 < NIT);
    const int k0 = 2 * i;
    short8 bfr[4][2];
    // ---- K-tile low (buf 0), phases P1..P4 ----
#pragma unroll
    for (int q = 0; q < 4; ++q) {
      if (q == 0) {
#pragma unroll
        for (int n = 0; n < 4; ++n)
#pragma unroll
          for (int kk = 0; kk < 2; ++kk) bfr[n][kk] = readB(0, n, kk);
      }
      short8 af[2][2];
#pragma unroll
      for (int mm = 0; mm < 2; ++mm)
#pragma unroll
        for (int kk = 0; kk < 2; ++kk) af[mm][kk] = readA(0, 2 * q + mm, kk);
      if (q == 0) stageA_(1, 0, k0 + 1);
      else if (q == 1) stageA_(1, 1, k0 + 1);
      else if (q == 2) { if (more) stageB_(0, 0, k0 + 2); }
      else             { if (more) stageB_(0, 1, k0 + 2); }
      BAR();
      __builtin_amdgcn_s_setprio(1);
#pragma unroll
      for (int mm = 0; mm < 2; ++mm)
#pragma unroll
        for (int n = 0; n < 4; ++n)
#pragma unroll
          for (int kk = 0; kk < 2; ++kk)
            acc[2 * q + mm][n] = mfma16(af[mm][kk], bfr[n][kk], acc[2 * q + mm][n]);
      __builtin_amdgcn_s_setprio(0);
      if (q == 3) { if (more) { VMCNT(4); } else { VMCNT(0); } }
      BAR();
    }
    // ---- K-tile high (buf 1), phases P5..P8 ----
#pragma unroll
    for (int q = 0; q < 4; ++q) {
      if (q == 0) {
#pragma unroll
        for (int n = 0; n < 4; ++n)
#pragma unroll
          for (int kk = 0; kk < 2; ++kk) bfr[n][kk] = readB(1, n, kk);
      }
      short8 af[2][2];
#pragma unroll
      for (int mm = 0; mm < 2; ++mm)
#pragma unroll
        for (int kk = 0; kk < 2; ++kk) af[mm][kk] = readA(1, 2 * q + mm, kk);
      if (more) {
        if (q == 0) stageA_(0, 0, k0 + 2);
        else if (q == 1) stageA_(0, 1, k0 + 2);
        else if (q == 2) stageB_(1, 0, k0 + 3);
        else stageB_(1, 1, k0 + 3);
      }
      BAR();
      __builtin_amdgcn_s_setprio(1);
#pragma unroll
      for (int mm = 0; mm < 2; ++mm)
#pragma unroll
        for (int n = 0; n < 4; ++n)
#pragma unroll
          for (int kk = 0; kk < 2; ++kk)
            acc[2 * q + mm][n] = mfma16(af[mm][kk], bfr[n][kk], acc[2 * q + mm][n]);
      __builtin_amdgcn_s_setprio(0);
      if (q == 3 && more) VMCNT(4);
      BAR();
    }
  }

  // epilogue: 16x16 D-frag layout col = lane&15, row = (lane>>4)*4 + j  [m89]
#pragma unroll
  for (int m = 0; m < 8; ++m) {
#pragma unroll
    for (int n = 0; n < 4; ++n) {
      int col = tN + wc * 64 + n * 16 + l15;
      int rbase = tM + wr * 128 + m * 16 + l16 * 4;
      if (FINAL) {
#pragma unroll
        for (int j = 0; j < 4; ++j)
          Cout[(size_t)(rbase + j) * 1024 + col] = acc[m][n][j];
      } else if (z == 2) {
        // VhT[bh][c][l]; 4 consecutive l -> packed 8B store
        int nh = col & 15, c = col >> 4;
        int b = rbase >> 11, l0 = rbase & 2047;
        B4 u;
#pragma unroll
        for (int j = 0; j < 4; ++j) u.h[j] = __float2bfloat16(acc[m][n][j]);
        *(int2*)&VhT[((size_t)(b * 16 + nh) * 64 + c) * 2048 + l0] = u.v;
      } else {
        bf16* dst = z ? Kh : Qh;  // Qh/Kh[bh][l][c]
        int nh = col & 15, c = col >> 4;
#pragma unroll
        for (int j = 0; j < 4; ++j) {
          int row = rbase + j;
          dst[((size_t)((row >> 11) * 16 + nh) * 2048 + (row & 2047)) * 64 + c] =
              __float2bfloat16(acc[m][n][j]);
        }
      }
    }
  }
}

// ---------------- flash attention, m214 structure (unchanged, validated) ----------------
__global__ __launch_bounds__(256) void attn_kernel(
    const bf16* __restrict__ Qh, const bf16* __restrict__ Kh,
    const bf16* __restrict__ VhT, bf16* __restrict__ Oh)
{
  __shared__ bf16 Kt[2][64 * 64];
  __shared__ bf16 Vt[2][64 * 64];
  const int t = threadIdx.x, lane = t & 63, w = t >> 6;
  const int l31 = lane & 31, hi = lane >> 5;
  const int bh = blockIdx.y;
  const int q0 = blockIdx.x * 128 + w * 32;
  const size_t baseQK = (size_t)bh * (2048 * 64);
  const size_t baseV  = (size_t)bh * (64 * 2048);

  short8 qf[4];
#pragma unroll
  for (int kc = 0; kc < 4; ++kc)
    qf[kc] = *(const short8*)&Qh[baseQK + (size_t)(q0 + l31) * 64 + kc * 16 + hi * 8];

  const int r0 = t >> 3, g0 = t & 7;
  const int sg = (g0 ^ (r0 & 7)) * 8;
  const bf16* ksrc0 = Kh  + baseQK + (size_t)r0 * 64 + sg;
  const bf16* ksrc1 = Kh  + baseQK + (size_t)(r0 + 32) * 64 + sg;
  const bf16* vsrc0 = VhT + baseV  + (size_t)r0 * 2048 + sg;
  const bf16* vsrc1 = VhT + baseV  + (size_t)(r0 + 32) * 2048 + sg;

  auto stage = [&](int buf, int ti) {
    GLD16(ksrc0 + (size_t)ti * 4096, &Kt[buf][t * 8]);
    GLD16(ksrc1 + (size_t)ti * 4096, &Kt[buf][2048 + t * 8]);
    GLD16(vsrc0 + ti * 64,           &Vt[buf][t * 8]);
    GLD16(vsrc1 + ti * 64,           &Vt[buf][2048 + t * 8]);
  };

  f32x16 o0 = ZV16, o1 = ZV16;
  float m = -1e30f, l = 0.f;
  const int swz = (l31 & 7);

  stage(0, 0);
  for (int ti = 0; ti < 32; ++ti) {
    const int buf = ti & 1;
    __syncthreads();
    if (ti < 31) stage(buf ^ 1, ti + 1);

    f32x16 s0 = ZV16, s1 = ZV16;
    __builtin_amdgcn_s_setprio(1);
#pragma unroll
    for (int kc = 0; kc < 4; ++kc) {
      const int gr = ((kc * 2 + hi) ^ swz) * 8;
      short8 kf0 = *(const short8*)&Kt[buf][l31 * 64 + gr];
      short8 kf1 = *(const short8*)&Kt[buf][(32 + l31) * 64 + gr];
      s0 = mfma32(kf0, qf[kc], s0);
      s1 = mfma32(kf1, qf[kc], s1);
    }
    __builtin_amdgcn_s_setprio(0);

    float tm8[8];
#pragma unroll
    for (int i2 = 0; i2 < 8; ++i2)
      tm8[i2] = fmaxf(fmaxf(s0[i2], s0[i2 + 8]), fmaxf(s1[i2], s1[i2 + 8]));
    float pm = fmaxf(fmaxf(fmaxf(tm8[0], tm8[1]), fmaxf(tm8[2], tm8[3])),
                     fmaxf(fmaxf(tm8[4], tm8[5]), fmaxf(tm8[6], tm8[7])));
    pm = fmaxf(pm, __shfl_xor(pm, 32));
    float mn = fmaxf(m, pm);
    float corr = fexp2((m - mn) * SC2f);
    m = mn;
    float nb = -mn * SC2f;
#pragma unroll
    for (int r = 0; r < 16; ++r) {
      s0[r] = fexp2(s0[r] * SC2f + nb);
      s1[r] = fexp2(s1[r] * SC2f + nb);
    }
    float ts8[8];
#pragma unroll
    for (int i2 = 0; i2 < 8; ++i2)
      ts8[i2] = (s0[i2] + s0[i2 + 8]) + (s1[i2] + s1[i2 + 8]);
    float rs = ((ts8[0] + ts8[1]) + (ts8[2] + ts8[3])) +
               ((ts8[4] + ts8[5]) + (ts8[6] + ts8[7]));
    rs += __shfl_xor(rs, 32);
    l = l * corr + rs;
#pragma unroll
    for (int r = 0; r < 16; ++r) { o0[r] *= corr; o1[r] *= corr; }

    short8 pf[4];
    {
      union U { int i[4]; short8 s8; } fr[4];
      int wds[16];
#pragma unroll
      for (int j = 0; j < 8; ++j) wds[j]     = cvtpk(s0[2 * j], s0[2 * j + 1]);
#pragma unroll
      for (int j = 0; j < 8; ++j) wds[8 + j] = cvtpk(s1[2 * j], s1[2 * j + 1]);
#pragma unroll
      for (int fb = 0; fb < 4; ++fb) {
        int a0 = wds[fb * 4 + 0], a1 = wds[fb * 4 + 1];
        int a2 = wds[fb * 4 + 2], a3 = wds[fb * 4 + 3];
#if __has_builtin(__builtin_amdgcn_permlane32_swap)
        auto s02 = __builtin_amdgcn_permlane32_swap(a0, a2, false, false);
        auto s13 = __builtin_amdgcn_permlane32_swap(a1, a3, false, false);
        fr[fb].i[0] = s02[0]; fr[fb].i[1] = s13[0];
        fr[fb].i[2] = s02[1]; fr[fb].i[3] = s13[1];
#else
        int x0 = __shfl_xor(a0, 32), x2 = __shfl_xor(a2, 32);
        int x1 = __shfl_xor(a1, 32), x3 = __shfl_xor(a3, 32);
        fr[fb].i[0] = hi ? x2 : a0; fr[fb].i[1] = hi ? x3 : a1;
        fr[fb].i[2] = hi ? a2 : x0; fr[fb].i[3] = hi ? a3 : x1;
#endif
        pf[fb] = fr[fb].s8;
      }
    }

    __builtin_amdgcn_s_setprio(1);
#pragma unroll
    for (int kc = 0; kc < 4; ++kc) {
      const int gr = ((kc * 2 + hi) ^ swz) * 8;
      short8 vf0 = *(const short8*)&Vt[buf][l31 * 64 + gr];
      short8 vf1 = *(const short8*)&Vt[buf][(32 + l31) * 64 + gr];
      o0 = mfma32(vf0, pf[kc], o0);
      o1 = mfma32(vf1, pf[kc], o1);
    }
    __builtin_amdgcn_s_setprio(0);
  }

  float rl = 1.0f / l;
  bf16* orow = Oh + baseQK + (size_t)(q0 + l31) * 64;
#pragma unroll
  for (int rq = 0; rq < 4; ++rq) {
    B4 u0, u1;
#pragma unroll
    for (int j = 0; j < 4; ++j) {
      u0.h[j] = __float2bfloat16(o0[rq * 4 + j] * rl);
      u1.h[j] = __float2bfloat16(o1[rq * 4 + j] * rl);
    }
    int dbase = rq * 8 + hi * 4;
    *(int2*)&orow[dbase]      = u0.v;
    *(int2*)&orow[32 + dbase] = u1.v;
  }
}

extern "C" void kernel_launch(void* const* d_in, const int* in_sizes, int n_in,
                              void* d_out, int out_size, void* d_ws, size_t ws_size,
                              hipStream_t stream) {
  const float* q  = (const float*)d_in[0];
  const float* k  = (const float*)d_in[1];
  const float* v  = (const float*)d_in[2];
  const float* Wq = (const float*)d_in[3];
  const float* Wk = (const float*)d_in[4];
  const float* Wv = (const float*)d_in[5];
  const float* Wo = (const float*)d_in[6];
  char* ws = (char*)d_ws;
  const size_t MB = 1u << 20;
  bf16* xb  = (bf16*)(ws);            // 24MB: q,k,v bf16 (dead after proj gemm)
  bf16* WT  = (bf16*)(ws + 24 * MB);  // 8MB: WqT,WkT,WvT,WoT'
  bf16* Qh  = (bf16*)(ws + 32 * MB);  // 8MB
  bf16* Kh  = (bf16*)(ws + 40 * MB);  // 8MB
  bf16* VhT = (bf16*)(ws + 48 * MB);  // 8MB
  bf16* Oh  = (bf16*)(ws);            // 8MB, reuses dead cast region

  cast3_kernel<<<dim3(2048, 3), 256, 0, stream>>>(q, k, v, xb);
  wtrans_kernel<<<dim3(16, 16, 4), 256, 0, stream>>>(Wq, Wk, Wv, Wo, WT);
  gemm8_kernel<0><<<dim3(4, 16, 3), 512, 0, stream>>>(xb, WT, Qh, Kh, VhT, nullptr);
  attn_kernel<<<dim3(16, 32), 256, 0, stream>>>(Qh, Kh, VhT, Oh);
  gemm8_kernel<1><<<dim3(4, 16), 512, 0, stream>>>(Oh, WT + 3 * (1u << 20), Qh, Kh, VhT,
                                                   (float*)d_out);
}

// Round 4
// 276.080 us; speedup vs baseline: 1.0898x; 1.0898x over previous
//
#include <hip/hip_runtime.h>
#include <hip/hip_bf16.h>

// AttnDecoder: B=2, Lq=Lkv=2048, E=1024, H=16, D=64, scale = 0.125/sqrt(2).
// Pipeline (all bf16 MFMA, fp32 accum):
//   cast3: q,k,v fp32 -> bf16 row-major           [ws +0 .. +24MB]
//   wtrans: Wq,Wk,Wv -> bf16 W^T (N x K); Wo -> permuted W^T folding head-merge
//   gemm8 (z=0..2): 256x256 8-phase GEMM (m201 template, UNPINNED) -> Qh,Kh,VhT
//   attn: m214-style 32x32 swapped-QK^T flash attention -> Oh [bh][l][c]
//   gemmo: 128x64-tile depth-2 triple-buffered GEMM, Oh @ WoT' -> d_out fp32
// Workspace required: 56 MB.

typedef __attribute__((ext_vector_type(8))) short short8;    // 8 x bf16 (4 VGPR)
typedef __attribute__((ext_vector_type(4))) float f32x4;     // 16x16 accumulator
typedef __attribute__((ext_vector_type(16))) float f32x16;   // 32x32 accumulator
typedef __hip_bfloat16 bf16;

#define GLD16(g, l) __builtin_amdgcn_global_load_lds( \
    (const __attribute__((address_space(1))) void*)(g), \
    (__attribute__((address_space(3))) void*)(l), 16, 0, 0)

// no sched_barrier pinning (m141: pinning -> 3x loss). "memory" clobber only.
#define VMCNT(n) asm volatile("s_waitcnt vmcnt(" #n ")" ::: "memory")
#define LGKM0()  asm volatile("s_waitcnt lgkmcnt(0)" ::: "memory")

__device__ __forceinline__ f32x4 mfma16(short8 a, short8 b, f32x4 c) {
  return __builtin_amdgcn_mfma_f32_16x16x32_bf16(a, b, c, 0, 0, 0);
}
__device__ __forceinline__ f32x16 mfma32(short8 a, short8 b, f32x16 c) {
  return __builtin_amdgcn_mfma_f32_32x32x16_bf16(a, b, c, 0, 0, 0);
}

union B8 { bf16 h[8]; int4 v; };
union B4 { bf16 h[4]; int2 v; };

#define QK_SCALE_TOT 0.08838834764831845f              /* 0.125 / sqrt(2) */
#define SC2f (QK_SCALE_TOT * 1.4426950408889634f)      /* -> exp2 domain */

__device__ __forceinline__ float fexp2(float x) {
#if __has_builtin(__builtin_amdgcn_exp2f)
  return __builtin_amdgcn_exp2f(x);
#else
  return exp2f(x);
#endif
}

__device__ __forceinline__ int cvtpk(float lo, float hi_) {
  int r;
  asm("v_cvt_pk_bf16_f32 %0, %1, %2" : "=v"(r) : "v"(lo), "v"(hi_));
  return r;
}

#define ZV16 {0.f,0.f,0.f,0.f,0.f,0.f,0.f,0.f,0.f,0.f,0.f,0.f,0.f,0.f,0.f,0.f}

// ---------------- cast q,k,v -> bf16 (vectorized, G13) ----------------
__global__ __launch_bounds__(256) void cast3_kernel(
    const float* __restrict__ q, const float* __restrict__ k,
    const float* __restrict__ v, bf16* __restrict__ out)
{
  const float* src = (blockIdx.y == 0) ? q : (blockIdx.y == 1) ? k : v;
  bf16* dst = out + (size_t)blockIdx.y * (4u << 20);
  size_t i = ((size_t)blockIdx.x * 256 + threadIdx.x) * 8;
  float4 a = *(const float4*)(src + i);
  float4 b = *(const float4*)(src + i + 4);
  B8 u;
  u.h[0] = __float2bfloat16(a.x); u.h[1] = __float2bfloat16(a.y);
  u.h[2] = __float2bfloat16(a.z); u.h[3] = __float2bfloat16(a.w);
  u.h[4] = __float2bfloat16(b.x); u.h[5] = __float2bfloat16(b.y);
  u.h[6] = __float2bfloat16(b.z); u.h[7] = __float2bfloat16(b.w);
  *(int4*)(dst + i) = u.v;
}

// ---------------- weight transpose (+ Wo head-merge permutation) ----------------
__global__ __launch_bounds__(256) void wtrans_kernel(
    const float* __restrict__ Wq, const float* __restrict__ Wk,
    const float* __restrict__ Wv, const float* __restrict__ Wo,
    bf16* __restrict__ dstbase)
{
  __shared__ bf16 ld[64][68];
  const int z = blockIdx.z;
  const float* src = (z == 0) ? Wq : (z == 1) ? Wk : (z == 2) ? Wv : Wo;
  bf16* dst = dstbase + (size_t)z * (1u << 20);
  const int k0 = blockIdx.x * 64, n0 = blockIdx.y * 64;
  const int t = threadIdx.x;
  const bool perm = (z == 3);
#pragma unroll
  for (int it = 0; it < 4; ++it) {
    int kk = it * 16 + (t >> 4);
    int K = k0 + kk;
    int j = perm ? ((K & 63) * 16 + (K >> 6)) : K;
    float4 vv = *(const float4*)(src + (size_t)j * 1024 + n0 + (t & 15) * 4);
    int c = (t & 15) * 4;
    ld[c + 0][kk] = __float2bfloat16(vv.x);
    ld[c + 1][kk] = __float2bfloat16(vv.y);
    ld[c + 2][kk] = __float2bfloat16(vv.z);
    ld[c + 3][kk] = __float2bfloat16(vv.w);
  }
  __syncthreads();
#pragma unroll
  for (int it = 0; it < 2; ++it) {
    int rr = it * 32 + (t >> 3), cc = (t & 7) * 8;
    B8 u;
#pragma unroll
    for (int e = 0; e < 8; ++e) u.h[e] = ld[rr][cc + e];
    *(int4*)(dst + (size_t)(n0 + rr) * 1024 + k0 + cc) = u.v;
  }
}

// ---------------- 256x256 8-phase projection GEMM (T2+T3+T4+T5), 8 waves ----------------
// Same vmcnt/stage schedule as r3 (logically verified there), but with the m141
// pinning removed: plain s_barrier + asm lgkmcnt(0), no sched_barrier(0).
__global__ __launch_bounds__(512, 2) void gemm8_kernel(
    const bf16* __restrict__ Abase, const bf16* __restrict__ WTbase,
    bf16* __restrict__ Qh, bf16* __restrict__ Kh, bf16* __restrict__ VhT)
{
  __shared__ bf16 lA[2][2][128 * 64];
  __shared__ bf16 lB[2][2][128 * 64];
  const int t = threadIdx.x, lane = t & 63, w = t >> 6;
  const int wr = w >> 2, wc = w & 3;                 // 2M x 4N waves
  const int l15 = lane & 15, l16 = lane >> 4;
  const int rswE = ((l15 >> 2) & 1) << 4;            // read-side swizzle (elems)
  // XCD swizzle within z: 64 blocks, chunked -> XCD k owns 2 M-panels x all N
  const int nblk = blockIdx.x + 4 * blockIdx.y;
  const int sblk = (nblk & 7) * 8 + (nblk >> 3);
  const int tN = (sblk & 3) * 256, tM = (sblk >> 2) * 256;
  const int z = blockIdx.z;
  const bf16* A  = Abase  + (size_t)z * (4u << 20);
  const bf16* BT = WTbase + (size_t)z * (1u << 20);

  // staging: thread covers LDS phys bytes o = (w*2+j)*1024 + lane*16 per half;
  // logical byte = o ^ ((o>>9)&1)<<5  (st_16x32, rule #21 source-side inverse).
  int oj[2], srj[2], scj[2];
#pragma unroll
  for (int j = 0; j < 2; ++j) {
    int o = (w * 2 + j) * 1024 + lane * 16;
    int lg = o ^ (((o >> 9) & 1) << 5);
    oj[j] = o >> 1;             // LDS elem offset
    srj[j] = lg >> 7;           // source row in half-tile (0..127)
    scj[j] = (lg & 127) >> 1;   // source col elem
  }
  size_t aRow[2][2], bRow[2][2];
#pragma unroll
  for (int h = 0; h < 2; ++h)
#pragma unroll
    for (int j = 0; j < 2; ++j) {
      aRow[h][j] = (size_t)(tM + h * 128 + srj[j]) * 1024 + scj[j];
      bRow[h][j] = (size_t)(tN + h * 128 + srj[j]) * 1024 + scj[j];
    }

  auto stageA_ = [&](int buf, int h, int kt) {
    GLD16(A + aRow[h][0] + (size_t)kt * 64, &lA[buf][h][oj[0]]);
    GLD16(A + aRow[h][1] + (size_t)kt * 64, &lA[buf][h][oj[1]]);
  };
  auto stageB_ = [&](int buf, int h, int kt) {
    GLD16(BT + bRow[h][0] + (size_t)kt * 64, &lB[buf][h][oj[0]]);
    GLD16(BT + bRow[h][1] + (size_t)kt * 64, &lB[buf][h][oj[1]]);
  };
  auto readA = [&](int buf, int m, int kk) -> short8 {
    return *(const short8*)&lA[buf][wr]
        [(m * 16 + l15) * 64 + ((kk * 32 + l16 * 8) ^ rswE)];
  };
  auto readB = [&](int buf, int n, int kk) -> short8 {
    return *(const short8*)&lB[buf][wc >> 1]
        [((wc & 1) * 64 + n * 16 + l15) * 64 + ((kk * 32 + l16 * 8) ^ rswE)];
  };

  f32x4 acc[8][4];
#pragma unroll
  for (int m = 0; m < 8; ++m)
#pragma unroll
    for (int n = 0; n < 4; ++n) acc[m][n] = {0.f, 0.f, 0.f, 0.f};

  // prologue: B0(kt0), A0(kt0), B1(kt1); leave B1's 4 loads outstanding.
  stageB_(0, 0, 0); stageB_(0, 1, 0);
  stageA_(0, 0, 0); stageA_(0, 1, 0);
  stageB_(1, 0, 1); stageB_(1, 1, 1);
  VMCNT(4);
  __builtin_amdgcn_s_barrier();

  const int NIT = 8;  // K = 1024 = NIT * 128
  for (int i = 0; i < NIT; ++i) {
    const bool more = (i + 1 < NIT);
    const int k0 = 2 * i;
    short8 bfr[4][2];
    // ---- K-tile low (buf 0), phases P1..P4 ----
#pragma unroll
    for (int q = 0; q < 4; ++q) {
      if (q == 0) {
#pragma unroll
        for (int n = 0; n < 4; ++n)
#pragma unroll
          for (int kk = 0; kk < 2; ++kk) bfr[n][kk] = readB(0, n, kk);
      }
      short8 af[2][2];
#pragma unroll
      for (int mm = 0; mm < 2; ++mm)
#pragma unroll
        for (int kk = 0; kk < 2; ++kk) af[mm][kk] = readA(0, 2 * q + mm, kk);
      if (q == 0) stageA_(1, 0, k0 + 1);
      else if (q == 1) stageA_(1, 1, k0 + 1);
      else if (q == 2) { if (more) stageB_(0, 0, k0 + 2); }
      else             { if (more) stageB_(0, 1, k0 + 2); }
      __builtin_amdgcn_s_barrier();
      LGKM0();
      __builtin_amdgcn_s_setprio(1);
#pragma unroll
      for (int mm = 0; mm < 2; ++mm)
#pragma unroll
        for (int n = 0; n < 4; ++n)
#pragma unroll
          for (int kk = 0; kk < 2; ++kk)
            acc[2 * q + mm][n] = mfma16(af[mm][kk], bfr[n][kk], acc[2 * q + mm][n]);
      __builtin_amdgcn_s_setprio(0);
      if (q == 3) { if (more) { VMCNT(4); } else { VMCNT(0); } }
      __builtin_amdgcn_s_barrier();
    }
    // ---- K-tile high (buf 1), phases P5..P8 ----
#pragma unroll
    for (int q = 0; q < 4; ++q) {
      if (q == 0) {
#pragma unroll
        for (int n = 0; n < 4; ++n)
#pragma unroll
          for (int kk = 0; kk < 2; ++kk) bfr[n][kk] = readB(1, n, kk);
      }
      short8 af[2][2];
#pragma unroll
      for (int mm = 0; mm < 2; ++mm)
#pragma unroll
        for (int kk = 0; kk < 2; ++kk) af[mm][kk] = readA(1, 2 * q + mm, kk);
      if (more) {
        if (q == 0) stageA_(0, 0, k0 + 2);
        else if (q == 1) stageA_(0, 1, k0 + 2);
        else if (q == 2) stageB_(1, 0, k0 + 3);
        else stageB_(1, 1, k0 + 3);
      }
      __builtin_amdgcn_s_barrier();
      LGKM0();
      __builtin_amdgcn_s_setprio(1);
#pragma unroll
      for (int mm = 0; mm < 2; ++mm)
#pragma unroll
        for (int n = 0; n < 4; ++n)
#pragma unroll
          for (int kk = 0; kk < 2; ++kk)
            acc[2 * q + mm][n] = mfma16(af[mm][kk], bfr[n][kk], acc[2 * q + mm][n]);
      __builtin_amdgcn_s_setprio(0);
      if (q == 3 && more) VMCNT(4);
      __builtin_amdgcn_s_barrier();
    }
  }

  // epilogue: 16x16 D-frag layout col = lane&15, row = (lane>>4)*4 + j  [m89]
#pragma unroll
  for (int m = 0; m < 8; ++m) {
#pragma unroll
    for (int n = 0; n < 4; ++n) {
      int col = tN + wc * 64 + n * 16 + l15;
      int rbase = tM + wr * 128 + m * 16 + l16 * 4;
      if (z == 2) {
        // VhT[bh][c][l]; 4 consecutive l -> packed 8B store
        int nh = col & 15, c = col >> 4;
        int b = rbase >> 11, l0 = rbase & 2047;
        B4 u;
#pragma unroll
        for (int j = 0; j < 4; ++j) u.h[j] = __float2bfloat16(acc[m][n][j]);
        *(int2*)&VhT[((size_t)(b * 16 + nh) * 64 + c) * 2048 + l0] = u.v;
      } else {
        bf16* dst = z ? Kh : Qh;  // Qh/Kh[bh][l][c]
        int nh = col & 15, c = col >> 4;
#pragma unroll
        for (int j = 0; j < 4; ++j) {
          int row = rbase + j;
          dst[((size_t)((row >> 11) * 16 + nh) * 2048 + (row & 2047)) * 64 + c] =
              __float2bfloat16(acc[m][n][j]);
        }
      }
    }
  }
}

// ---------------- final GEMM: Oh (head-merge folded) @ WoT' -> fp32 out ----------------
// 128x64 tiles, 512 blocks (2/CU), 4 waves (2x2), per-wave 64x32.
// Triple-buffered depth-2: stage kt+2 while computing kt; vmcnt(6) checkpoints
// keep the next K-step's 6 loads in flight (T4). Granule-XOR LDS swizzle.
__global__ __launch_bounds__(256) void gemmo_kernel(
    const bf16* __restrict__ Oh, const bf16* __restrict__ WoT,
    float* __restrict__ Cout)
{
  __shared__ bf16 lA[3][128 * 64];
  __shared__ bf16 lB[3][64 * 64];
  const int t = threadIdx.x, lane = t & 63, w = t >> 6;
  const int wr = w >> 1, wc = w & 1;
  const int l15 = lane & 15, l16 = lane >> 4;
  const int gsw = l15 & 7;
  // XCD swizzle: 512 blocks; XCD k owns 4 M-panels x all N (Wo' L2-resident)
  const int nblk = blockIdx.x + 16 * blockIdx.y;
  const int sblk = (nblk & 7) * 64 + (nblk >> 3);
  const int tN = (sblk & 15) * 64, tM = (sblk >> 4) * 128;

  // staging sources: thread t covers phys granule (i*256+t); phys g&7 = t&7,
  // row = i*32 + (t>>3); logical col granule = (t&7) ^ (row&7).
  const int ca = (((t & 7) ^ ((t >> 3) & 7)) * 8);
  size_t aoff[4], boff[2];
#pragma unroll
  for (int i = 0; i < 4; ++i) {
    int rg = tM + i * 32 + (t >> 3);
    // Oh[bh = b*16 + kt][l][c]: K-tile kt == head index
    aoff[i] = ((size_t)(rg >> 11) * 16 * 2048 + (rg & 2047)) * 64 + ca;
  }
#pragma unroll
  for (int i = 0; i < 2; ++i)
    boff[i] = (size_t)(tN + i * 32 + (t >> 3)) * 1024 + ca;

  auto stage = [&](int b, int kt) {
#pragma unroll
    for (int i = 0; i < 4; ++i)
      GLD16(Oh + aoff[i] + (size_t)kt * (2048 * 64), &lA[b][(i * 256 + t) * 8]);
#pragma unroll
    for (int i = 0; i < 2; ++i)
      GLD16(WoT + boff[i] + kt * 64, &lB[b][(i * 256 + t) * 8]);
  };

  f32x4 acc[4][2];
#pragma unroll
  for (int m = 0; m < 4; ++m)
#pragma unroll
    for (int n = 0; n < 2; ++n) acc[m][n] = {0.f, 0.f, 0.f, 0.f};

  stage(0, 0); stage(1, 1);
  VMCNT(6);                       // drain kt0's 6, leave kt1's in flight
  __builtin_amdgcn_s_barrier();

  int bR = 0, bS = 2;
  for (int kt = 0; kt < 16; ++kt) {
    if (kt < 14) stage(bS, kt + 2);
    short8 a_[4][2], b_[2][2];
#pragma unroll
    for (int m = 0; m < 4; ++m)
#pragma unroll
      for (int kk = 0; kk < 2; ++kk) {
        int row = wr * 64 + m * 16 + l15;
        a_[m][kk] = *(const short8*)&lA[bR][row * 64 + (((kk * 4 + l16) ^ gsw) * 8)];
      }
#pragma unroll
    for (int n = 0; n < 2; ++n)
#pragma unroll
      for (int kk = 0; kk < 2; ++kk) {
        int row = wc * 32 + n * 16 + l15;
        b_[n][kk] = *(const short8*)&lB[bR][row * 64 + (((kk * 4 + l16) ^ gsw) * 8)];
      }
#pragma unroll
    for (int kk = 0; kk < 2; ++kk)
#pragma unroll
      for (int m = 0; m < 4; ++m)
#pragma unroll
        for (int n = 0; n < 2; ++n)
          acc[m][n] = mfma16(a_[m][kk], b_[n][kk], acc[m][n]);
    if (kt < 14) { VMCNT(6); } else { VMCNT(0); }
    __builtin_amdgcn_s_barrier();
    bR = (bR == 2) ? 0 : bR + 1;
    bS = (bS == 2) ? 0 : bS + 1;
  }

#pragma unroll
  for (int m = 0; m < 4; ++m)
#pragma unroll
    for (int n = 0; n < 2; ++n) {
      int col = tN + wc * 32 + n * 16 + l15;
      int rbase = tM + wr * 64 + m * 16 + l16 * 4;
#pragma unroll
      for (int j = 0; j < 4; ++j)
        Cout[(size_t)(rbase + j) * 1024 + col] = acc[m][n][j];
    }
}

// ---------------- flash attention, m214 structure (unchanged, validated) ----------------
__global__ __launch_bounds__(256) void attn_kernel(
    const bf16* __restrict__ Qh, const bf16* __restrict__ Kh,
    const bf16* __restrict__ VhT, bf16* __restrict__ Oh)
{
  __shared__ bf16 Kt[2][64 * 64];
  __shared__ bf16 Vt[2][64 * 64];
  const int t = threadIdx.x, lane = t & 63, w = t >> 6;
  const int l31 = lane & 31, hi = lane >> 5;
  const int bh = blockIdx.y;
  const int q0 = blockIdx.x * 128 + w * 32;
  const size_t baseQK = (size_t)bh * (2048 * 64);
  const size_t baseV  = (size_t)bh * (64 * 2048);

  short8 qf[4];
#pragma unroll
  for (int kc = 0; kc < 4; ++kc)
    qf[kc] = *(const short8*)&Qh[baseQK + (size_t)(q0 + l31) * 64 + kc * 16 + hi * 8];

  const int r0 = t >> 3, g0 = t & 7;
  const int sg = (g0 ^ (r0 & 7)) * 8;
  const bf16* ksrc0 = Kh  + baseQK + (size_t)r0 * 64 + sg;
  const bf16* ksrc1 = Kh  + baseQK + (size_t)(r0 + 32) * 64 + sg;
  const bf16* vsrc0 = VhT + baseV  + (size_t)r0 * 2048 + sg;
  const bf16* vsrc1 = VhT + baseV  + (size_t)(r0 + 32) * 2048 + sg;

  auto stage = [&](int buf, int ti) {
    GLD16(ksrc0 + (size_t)ti * 4096, &Kt[buf][t * 8]);
    GLD16(ksrc1 + (size_t)ti * 4096, &Kt[buf][2048 + t * 8]);
    GLD16(vsrc0 + ti * 64,           &Vt[buf][t * 8]);
    GLD16(vsrc1 + ti * 64,           &Vt[buf][2048 + t * 8]);
  };

  f32x16 o0 = ZV16, o1 = ZV16;
  float m = -1e30f, l = 0.f;
  const int swz = (l31 & 7);

  stage(0, 0);
  for (int ti = 0; ti < 32; ++ti) {
    const int buf = ti & 1;
    __syncthreads();
    if (ti < 31) stage(buf ^ 1, ti + 1);

    f32x16 s0 = ZV16, s1 = ZV16;
    __builtin_amdgcn_s_setprio(1);
#pragma unroll
    for (int kc = 0; kc < 4; ++kc) {
      const int gr = ((kc * 2 + hi) ^ swz) * 8;
      short8 kf0 = *(const short8*)&Kt[buf][l31 * 64 + gr];
      short8 kf1 = *(const short8*)&Kt[buf][(32 + l31) * 64 + gr];
      s0 = mfma32(kf0, qf[kc], s0);
      s1 = mfma32(kf1, qf[kc], s1);
    }
    __builtin_amdgcn_s_setprio(0);

    float tm8[8];
#pragma unroll
    for (int i2 = 0; i2 < 8; ++i2)
      tm8[i2] = fmaxf(fmaxf(s0[i2], s0[i2 + 8]), fmaxf(s1[i2], s1[i2 + 8]));
    float pm = fmaxf(fmaxf(fmaxf(tm8[0], tm8[1]), fmaxf(tm8[2], tm8[3])),
                     fmaxf(fmaxf(tm8[4], tm8[5]), fmaxf(tm8[6], tm8[7])));
    pm = fmaxf(pm, __shfl_xor(pm, 32));
    float mn = fmaxf(m, pm);
    float corr = fexp2((m - mn) * SC2f);
    m = mn;
    float nb = -mn * SC2f;
#pragma unroll
    for (int r = 0; r < 16; ++r) {
      s0[r] = fexp2(s0[r] * SC2f + nb);
      s1[r] = fexp2(s1[r] * SC2f + nb);
    }
    float ts8[8];
#pragma unroll
    for (int i2 = 0; i2 < 8; ++i2)
      ts8[i2] = (s0[i2] + s0[i2 + 8]) + (s1[i2] + s1[i2 + 8]);
    float rs = ((ts8[0] + ts8[1]) + (ts8[2] + ts8[3])) +
               ((ts8[4] + ts8[5]) + (ts8[6] + ts8[7]));
    rs += __shfl_xor(rs, 32);
    l = l * corr + rs;
#pragma unroll
    for (int r = 0; r < 16; ++r) { o0[r] *= corr; o1[r] *= corr; }

    short8 pf[4];
    {
      union U { int i[4]; short8 s8; } fr[4];
      int wds[16];
#pragma unroll
      for (int j = 0; j < 8; ++j) wds[j]     = cvtpk(s0[2 * j], s0[2 * j + 1]);
#pragma unroll
      for (int j = 0; j < 8; ++j) wds[8 + j] = cvtpk(s1[2 * j], s1[2 * j + 1]);
#pragma unroll
      for (int fb = 0; fb < 4; ++fb) {
        int a0 = wds[fb * 4 + 0], a1 = wds[fb * 4 + 1];
        int a2 = wds[fb * 4 + 2], a3 = wds[fb * 4 + 3];
#if __has_builtin(__builtin_amdgcn_permlane32_swap)
        auto s02 = __builtin_amdgcn_permlane32_swap(a0, a2, false, false);
        auto s13 = __builtin_amdgcn_permlane32_swap(a1, a3, false, false);
        fr[fb].i[0] = s02[0]; fr[fb].i[1] = s13[0];
        fr[fb].i[2] = s02[1]; fr[fb].i[3] = s13[1];
#else
        int x0 = __shfl_xor(a0, 32), x2 = __shfl_xor(a2, 32);
        int x1 = __shfl_xor(a1, 32), x3 = __shfl_xor(a3, 32);
        fr[fb].i[0] = hi ? x2 : a0; fr[fb].i[1] = hi ? x3 : a1;
        fr[fb].i[2] = hi ? a2 : x0; fr[fb].i[3] = hi ? a3 : x1;
#endif
        pf[fb] = fr[fb].s8;
      }
    }

    __builtin_amdgcn_s_setprio(1);
#pragma unroll
    for (int kc = 0; kc < 4; ++kc) {
      const int gr = ((kc * 2 + hi) ^ swz) * 8;
      short8 vf0 = *(const short8*)&Vt[buf][l31 * 64 + gr];
      short8 vf1 = *(const short8*)&Vt[buf][(32 + l31) * 64 + gr];
      o0 = mfma32(vf0, pf[kc], o0);
      o1 = mfma32(vf1, pf[kc], o1);
    }
    __builtin_amdgcn_s_setprio(0);
  }

  float rl = 1.0f / l;
  bf16* orow = Oh + baseQK + (size_t)(q0 + l31) * 64;
#pragma unroll
  for (int rq = 0; rq < 4; ++rq) {
    B4 u0, u1;
#pragma unroll
    for (int j = 0; j < 4; ++j) {
      u0.h[j] = __float2bfloat16(o0[rq * 4 + j] * rl);
      u1.h[j] = __float2bfloat16(o1[rq * 4 + j] * rl);
    }
    int dbase = rq * 8 + hi * 4;
    *(int2*)&orow[dbase]      = u0.v;
    *(int2*)&orow[32 + dbase] = u1.v;
  }
}

extern "C" void kernel_launch(void* const* d_in, const int* in_sizes, int n_in,
                              void* d_out, int out_size, void* d_ws, size_t ws_size,
                              hipStream_t stream) {
  const float* q  = (const float*)d_in[0];
  const float* k  = (const float*)d_in[1];
  const float* v  = (const float*)d_in[2];
  const float* Wq = (const float*)d_in[3];
  const float* Wk = (const float*)d_in[4];
  const float* Wv = (const float*)d_in[5];
  const float* Wo = (const float*)d_in[6];
  char* ws = (char*)d_ws;
  const size_t MB = 1u << 20;
  bf16* xb  = (bf16*)(ws);            // 24MB: q,k,v bf16 (dead after proj gemm)
  bf16* WT  = (bf16*)(ws + 24 * MB);  // 8MB: WqT,WkT,WvT,WoT'
  bf16* Qh  = (bf16*)(ws + 32 * MB);  // 8MB
  bf16* Kh  = (bf16*)(ws + 40 * MB);  // 8MB
  bf16* VhT = (bf16*)(ws + 48 * MB);  // 8MB
  bf16* Oh  = (bf16*)(ws);            // 8MB, reuses dead cast region

  cast3_kernel<<<dim3(2048, 3), 256, 0, stream>>>(q, k, v, xb);
  wtrans_kernel<<<dim3(16, 16, 4), 256, 0, stream>>>(Wq, Wk, Wv, Wo, WT);
  gemm8_kernel<<<dim3(4, 16, 3), 512, 0, stream>>>(xb, WT, Qh, Kh, VhT);
  attn_kernel<<<dim3(16, 32), 256, 0, stream>>>(Qh, Kh, VhT, Oh);
  gemmo_kernel<<<dim3(16, 32), 256, 0, stream>>>(Oh, WT + 3 * (1u << 20),
                                                 (float*)d_out);
}